// Round 1
// baseline (1739.833 us; speedup 1.0000x reference)
//
#include <hip/hip_runtime.h>
#include <math.h>

#define H   128
#define G4  512   // 4*H
#define TT  128   // timesteps
#define BB  8     // batch

__device__ __forceinline__ float sigf(float x) { return 1.0f / (1.0f + expf(-x)); }

// ---------------------------------------------------------------------------
// prep: transpose w_ih1 and w_hh1 into [k4][r] float4 layout in ws so that
// phase-C streaming loads are coalesced across the 512 threads (lane = r).
// ws4[m*16384 + k4*512 + r] = w[m][r][4*k4 .. 4*k4+3]
// ---------------------------------------------------------------------------
__global__ void prep_kernel(const float* __restrict__ w_ih1,
                            const float* __restrict__ w_hh1,
                            float4* __restrict__ ws4) {
    int id  = blockIdx.x * 256 + threadIdx.x;   // 0 .. 32767
    int m   = id >> 14;                          // 0: w_ih1, 1: w_hh1
    int rem = id & 16383;
    int k4  = rem >> 9;                          // 0 .. 31
    int r   = rem & 511;                         // 0 .. 511
    const float* src = m ? w_hh1 : w_ih1;
    float4 v = *reinterpret_cast<const float4*>(src + r * H + k4 * 4);
    ws4[m * 16384 + k4 * 512 + r] = v;
}

// ---------------------------------------------------------------------------
// main: one block per batch element, 512 threads = one thread per gate row.
// Sequential over t. w_hh0 row register-resident; w_ih1/w_hh1 streamed.
// Writes g[b,t] = dy[t]/du[t] into gbuf.
// ---------------------------------------------------------------------------
__global__ __launch_bounds__(512, 2)
void lstm_kernel(const float* __restrict__ x,
                 const float* __restrict__ w_ih0,
                 const float* __restrict__ w_hh0,
                 const float* __restrict__ b_ih0,
                 const float* __restrict__ b_hh0,
                 const float* __restrict__ b_ih1,
                 const float* __restrict__ b_hh1,
                 const float* __restrict__ w_out,
                 const float4* __restrict__ wiT4,   // [32][512] transposed w_ih1
                 const float4* __restrict__ whT4,   // [32][512] transposed w_hh1
                 float* __restrict__ gbuf) {
    __shared__ float4 h1s4[H / 4];
    __shared__ float4 h2s4[H / 4];
    __shared__ float4 vs4[H / 4];
    __shared__ float  zbuf[G4];
    __shared__ float  dzbuf[G4];
    __shared__ float  u_s[TT];
    __shared__ float  wcol_s[G4];
    __shared__ float  red[2];

    float* h1s = (float*)h1s4;
    float* h2s = (float*)h2s4;
    float* vs  = (float*)vs4;

    const int b = blockIdx.x;
    const int r = threadIdx.x;

    const float wcol  = w_ih0[r];             // w_ih0 is [512,1]
    const float bias0 = b_ih0[r] + b_hh0[r];
    const float bias1 = b_ih1[r] + b_hh1[r];
    wcol_s[r] = wcol;

    // register-resident w_hh0 row r (contiguous, 128 floats = 32 float4)
    float4 wh0[32];
    const float4* wrow = reinterpret_cast<const float4*>(w_hh0 + r * H);
#pragma unroll
    for (int q = 0; q < 32; q++) wh0[q] = wrow[q];

    float c1 = 0.f, c2 = 0.f, wout = 0.f;
    if (r < H) {
        h1s[r] = 0.f;
        h2s[r] = 0.f;
        // u[t] = trace(x[b,t]) ; thread r computes t = r
        const float* xb = x + (b * TT + r) * 1024;
        float u = 0.f;
#pragma unroll
        for (int i = 0; i < 32; i++) u += xb[i * 33];
        u_s[r] = u;
        wout = w_out[r];
    }
    __syncthreads();

    for (int t = 0; t < TT; t++) {
        // ---- phase A: layer-1 pre-activations (all 512 rows) ----
        float acc = fmaf(wcol, u_s[t], bias0);
#pragma unroll
        for (int q = 0; q < 32; q++) {
            float4 hh = h1s4[q];
            float4 w  = wh0[q];
            acc = fmaf(w.x, hh.x, acc);
            acc = fmaf(w.y, hh.y, acc);
            acc = fmaf(w.z, hh.z, acc);
            acc = fmaf(w.w, hh.w, acc);
        }
        zbuf[r] = acc;
        __syncthreads();

        // ---- phase B: layer-1 elementwise + tangent (threads 0..127) ----
        if (r < H) {
            float i1 = sigf(zbuf[r]);
            float f1 = sigf(zbuf[r + 128]);
            float g1 = tanhf(zbuf[r + 256]);
            float o1 = sigf(zbuf[r + 384]);
            float di = i1 * (1.f - i1) * wcol_s[r];
            float df = f1 * (1.f - f1) * wcol_s[r + 128];
            float dg = (1.f - g1 * g1) * wcol_s[r + 256];
            float dob = o1 * (1.f - o1) * wcol_s[r + 384];
            float dc1 = df * c1 + di * g1 + i1 * dg;   // c1 here is c1[t-1]
            c1 = f1 * c1 + i1 * g1;
            float th  = tanhf(c1);
            float h1n = o1 * th;
            float dh1 = dob * th + o1 * (1.f - th * th) * dc1;
            h1s[r] = h1n;
            vs[r]  = dh1;
        }
        __syncthreads();

        // ---- phase C: layer-2 pre-activations + tangent matvec ----
        float a2 = bias1;
        float ad = 0.f;
#pragma unroll
        for (int q = 0; q < 32; q++) {
            float4 wi  = wiT4[q * 512 + r];
            float4 wh  = whT4[q * 512 + r];
            float4 h1v = h1s4[q];
            float4 h2v = h2s4[q];
            float4 vv  = vs4[q];
            a2 = fmaf(wi.x, h1v.x, a2);
            a2 = fmaf(wi.y, h1v.y, a2);
            a2 = fmaf(wi.z, h1v.z, a2);
            a2 = fmaf(wi.w, h1v.w, a2);
            a2 = fmaf(wh.x, h2v.x, a2);
            a2 = fmaf(wh.y, h2v.y, a2);
            a2 = fmaf(wh.z, h2v.z, a2);
            a2 = fmaf(wh.w, h2v.w, a2);
            ad = fmaf(wi.x, vv.x, ad);
            ad = fmaf(wi.y, vv.y, ad);
            ad = fmaf(wi.z, vv.z, ad);
            ad = fmaf(wi.w, vv.w, ad);
        }
        zbuf[r]  = a2;
        dzbuf[r] = ad;
        __syncthreads();

        // ---- phase D: layer-2 elementwise + output tangent (threads 0..127) ----
        if (r < H) {
            float i2 = sigf(zbuf[r]);
            float f2 = sigf(zbuf[r + 128]);
            float g2 = tanhf(zbuf[r + 256]);
            float o2 = sigf(zbuf[r + 384]);
            float di2 = i2 * (1.f - i2) * dzbuf[r];
            float df2 = f2 * (1.f - f2) * dzbuf[r + 128];
            float dg2 = (1.f - g2 * g2) * dzbuf[r + 256];
            float do2 = o2 * (1.f - o2) * dzbuf[r + 384];
            float dc2 = df2 * c2 + di2 * g2 + i2 * dg2;  // c2 here is c2[t-1]
            c2 = f2 * c2 + i2 * g2;
            float th2 = tanhf(c2);
            h2s[r] = o2 * th2;
            float dh2 = do2 * th2 + o2 * (1.f - th2 * th2) * dc2;
            float p = wout * dh2;
#pragma unroll
            for (int d = 32; d > 0; d >>= 1) p += __shfl_down(p, d, 64);
            if ((r & 63) == 0) red[r >> 6] = p;
        }
        __syncthreads();
        if (r == 0) gbuf[b * TT + t] = red[0] + red[1];
        // safe: red is next written in phase D of t+1, after 3 more barriers
    }
}

// ---------------------------------------------------------------------------
// fill: out[b,t,i,j] = (i==j) ? g[b,t] : 0  over the full 4 MB output.
// ---------------------------------------------------------------------------
__global__ void fill_kernel(const float* __restrict__ gbuf,
                            float4* __restrict__ out4) {
    int id   = blockIdx.x * 256 + threadIdx.x;  // 0 .. 262143
    int base = id * 4;
    int j0   = base & 31;
    int i    = (base >> 5) & 31;
    int bt   = base >> 10;                      // 0 .. 1023
    float g  = gbuf[bt];
    float4 v;
    v.x = (j0     == i) ? g : 0.f;
    v.y = (j0 + 1 == i) ? g : 0.f;
    v.z = (j0 + 2 == i) ? g : 0.f;
    v.w = (j0 + 3 == i) ? g : 0.f;
    out4[id] = v;
}

extern "C" void kernel_launch(void* const* d_in, const int* in_sizes, int n_in,
                              void* d_out, int out_size, void* d_ws, size_t ws_size,
                              hipStream_t stream) {
    const float* x     = (const float*)d_in[0];
    const float* w_ih0 = (const float*)d_in[1];
    const float* w_hh0 = (const float*)d_in[2];
    const float* b_ih0 = (const float*)d_in[3];
    const float* b_hh0 = (const float*)d_in[4];
    const float* w_ih1 = (const float*)d_in[5];
    const float* w_hh1 = (const float*)d_in[6];
    const float* b_ih1 = (const float*)d_in[7];
    const float* b_hh1 = (const float*)d_in[8];
    const float* w_out = (const float*)d_in[9];
    // d_in[10] = b_out: constant offset, zero derivative -> unused

    float4* ws4  = (float4*)d_ws;              // 32768 float4 = 512 KB transposed weights
    float*  gbuf = (float*)d_ws + 2 * 65536;   // 1024 floats g[b,t]

    prep_kernel<<<dim3(128), dim3(256), 0, stream>>>(w_ih1, w_hh1, ws4);
    lstm_kernel<<<dim3(BB), dim3(512), 0, stream>>>(x, w_ih0, w_hh0, b_ih0, b_hh0,
                                                    b_ih1, b_hh1, w_out,
                                                    ws4, ws4 + 16384, gbuf);
    fill_kernel<<<dim3(1024), dim3(256), 0, stream>>>(gbuf, (float4*)d_out);
}